// Round 11
// baseline (752.800 us; speedup 1.0000x reference)
//
#include <hip/hip_runtime.h>

// DepthFlowProjection (DAIN, fillhole=0) forward — LDS box-splat scatter.
// R11 = R9's proven tile kernel (float4 row loads, stride-4 lane mapping,
// 2-deep pipeline, 167us) + R10's validated compact leak LIST (wave-
// aggregated append) replacing the 132MB leak-cell image (+memset+image
// finalize). R10 lesson: the float[9]/scalar-load rewrite spilled to
// scratch under the 8-waves/EU VGPR budget (FETCH +60MB, VALU 7.7%) — do
// not touch the R9 register structure.

constexpr int W  = 1920, H = 1080;
constexpr int HW = W * H;
constexpr int Sh = 20, Wt = 128, R = 24;
constexpr int TX = W / Wt, TY = H / Sh;     // 15, 54
constexpr int SW = Sh * Wt;                 // 2560 outputs per tile
constexpr int SP = (Sh + 1) * (Wt + 1);     // 2709 S-cells per plane (stride 129)
constexpr int ACCN = (3 * SP + 3) & ~3;     // 8128 floats (32.5 KB)
constexpr float LEAK_THR = (float)(R - 1);  // 23.0f

__global__ __launch_bounds__(512, 8) void dfp_tile(
    const float* __restrict__ flow, const float* __restrict__ depth,
    float* __restrict__ cnt_out,      // [B*HW] raw tile cnt plane
    unsigned* __restrict__ leak_cnt,  // [1], zeroed
    float4* __restrict__ leak_list, unsigned leak_cap,
    float* __restrict__ out, int B)
{
    __shared__ __align__(16) float acc[ACCN];   // S planes: cnt, sx, sy
    const int tid  = threadIdx.x;
    const int lane = tid & 63;
    const int wid  = tid >> 6;

    // XCD-aware swizzle (grid = 3240, mod 8 == 0 -> simple bijective form)
    int nwg  = gridDim.x;
    int orig = blockIdx.x;
    int blk  = ((nwg & 7) == 0) ? (orig & 7) * (nwg >> 3) + (orig >> 3) : orig;

    int b  = blk / (TX * TY);
    int t  = blk - b * (TX * TY);
    int ty = t / TX;
    int tx = t - ty * TX;
    const int Y0 = ty * Sh, X0 = tx * Wt;

    float4* accv = (float4*)acc;
    for (int i = tid; i < ACCN / 4; i += 512)
        accv[i] = make_float4(0.f, 0.f, 0.f, 0.f);
    __syncthreads();

    const float* fxp = flow + (size_t)b * 2 * HW;
    const float* fyp = fxp + HW;
    const float* dp  = depth + (size_t)b * HW;

    const int r0 = max(Y0 - R, 0), r1 = min(Y0 + Sh + R, H);
    const int c0 = max(X0 - R, 0), c1 = min(X0 + Wt + R, W);
    // c1-c0 is a multiple of 4 (X0 mult of 128, R=24, W=1920)
    const int nlv = (c1 - c0) >> 2;      // # valid lanes (<= 44)
    const int ce  = c0 + (lane << 2);
    const int cl  = min(ce, c1 - 4);

    auto ldrow = [&](int r, float4& f4x, float4& f4y, float4& d4) {
        size_t p = (size_t)r * W + cl;
        f4x = *(const float4*)(fxp + p);
        f4y = *(const float4*)(fyp + p);
        d4  = *(const float4*)(dp  + p);
    };

    auto proc1 = [&](int row, int col, float fx, float fy, float dv) {
        float x2 = (float)col + fx;
        float y2 = (float)row + fy;
        if (!(x2 >= 0.f && y2 >= 0.f && x2 <= (float)(W - 1) && y2 <= (float)(H - 1)))
            return;
        int ixL = (int)floorf(x2);    // valid => in [0, W-1]
        int iyT = (int)floorf(y2);    // valid => in [0, H-1]
        float vx = -fx * dv, vy = -fy * dv;
        bool small = (fabsf(fx) <= LEAK_THR) && (fabsf(fy) <= LEAK_THR);
        bool dup   = (ixL >= W - 1) | (iyT >= H - 1);  // border clamp dup case

        if (small && !dup) {
            // base-corner accumulate into overlapping S-window
            // (boundary rows/cols stored by BOTH adjacent tiles; each copy
            // feeds only that tile's exclusive outputs -> exact)
            int a = iyT - Y0 + 1;
            int c = ixL - X0 + 1;
            if ((unsigned)a < (unsigned)(Sh + 1) && (unsigned)c < (unsigned)(Wt + 1)) {
                int o = a * (Wt + 1) + c;
                atomicAdd(&acc[o],          dv);
                atomicAdd(&acc[o + SP],     vx);
                atomicAdd(&acc[o + 2*SP],   vy);
            }
        } else if ((unsigned)(row - Y0) < (unsigned)Sh &&
                   (unsigned)(col - X0) < (unsigned)Wt) {
            // rare pixel (big flow / border dup): append one record, once,
            // by its source-owning tile. Wave-aggregated counter bump.
            unsigned long long mask = __ballot(1);
            int nact   = __popcll(mask);
            int prefix = __popcll(mask & ((1ull << lane) - 1));
            unsigned basei = 0;
            if (prefix == 0) basei = atomicAdd(leak_cnt, (unsigned)nact);
            int leader = __ffsll((unsigned long long)mask) - 1;
            basei = __shfl(basei, leader);
            unsigned idx2 = basei + (unsigned)prefix;
            if (idx2 < leak_cap)
                leak_list[idx2] = make_float4(
                    __int_as_float(b * HW + iyT * W + ixL), dv, vx, vy);
        }
    };

    auto proc4 = [&](int row, const float4& f4x, const float4& f4y, const float4& d4) {
        if (lane >= nlv) return;         // duplicate tail lanes: nothing to do
        proc1(row, cl + 0, f4x.x, f4y.x, d4.x);
        proc1(row, cl + 1, f4x.y, f4y.y, d4.y);
        proc1(row, cl + 2, f4x.z, f4y.z, d4.z);
        proc1(row, cl + 3, f4x.w, f4y.w, d4.w);
    };

    // 2-deep software-pipelined row loop; named slots A/B (static indexing)
    int r = r0 + wid;
    float4 fxA, fyA, dA, fxB, fyB, dB;
    if (r     < r1) ldrow(r,     fxA, fyA, dA);
    if (r + 8 < r1) ldrow(r + 8, fxB, fyB, dB);
    while (r < r1) {
        if (r + 16 < r1) {
            float4 t1, t2, t3;
            ldrow(r + 16, t1, t2, t3);
            proc4(r, fxA, fyA, dA);
            fxA = t1; fyA = t2; dA = t3;
        } else {
            proc4(r, fxA, fyA, dA);
        }
        r += 8;
        if (r >= r1) break;
        if (r + 16 < r1) {
            float4 t1, t2, t3;
            ldrow(r + 16, t1, t2, t3);
            proc4(r, fxB, fyB, dB);
            fxB = t1; fyB = t2; dB = t3;
        } else {
            proc4(r, fxB, fyB, dB);
        }
        r += 8;
    }
    __syncthreads();

    // flush: 2x2 window sum of S -> raw output sums (exclusive ownership)
    float* outx = out + (size_t)b * 2 * HW;
    float* outy = outx + HW;
    for (int i = tid; i < SW; i += 512) {
        int ly = i >> 7;            // Wt = 128
        int lx = i & 127;
        int o  = ly * (Wt + 1) + lx;
        float cnt = acc[o]        + acc[o + 1]
                  + acc[o + Wt+1] + acc[o + Wt+2];
        float sx  = acc[SP + o]        + acc[SP + o + 1]
                  + acc[SP + o + Wt+1] + acc[SP + o + Wt+2];
        float sy  = acc[2*SP + o]        + acc[2*SP + o + 1]
                  + acc[2*SP + o + Wt+1] + acc[2*SP + o + Wt+2];
        int gp = (Y0 + ly) * W + (X0 + lx);
        outx[gp] = sx;
        outy[gp] = sy;
        cnt_out[(size_t)b * HW + gp] = cnt;
    }
}

// Kernel 2: apply leak records (reference-style 4 clamped corners) via
// global atomics into the raw sums. Stream-ordered after dfp_tile.
__global__ void dfp_leak_apply(const float4* __restrict__ list,
                               const unsigned* __restrict__ n_ptr,
                               float* __restrict__ out,
                               float* __restrict__ cnt_plane,
                               unsigned cap, int B)
{
    unsigned n = *n_ptr;
    if (n > cap) n = cap;
    for (unsigned i = blockIdx.x * blockDim.x + threadIdx.x; i < n;
         i += gridDim.x * blockDim.x) {
        float4 rec = list[i];
        int pos = __float_as_int(rec.x);
        int bb  = pos / HW;
        int p   = pos - bb * HW;
        int iyT = p / W;
        int ixL = p - iyT * W;
        int ixR = min(ixL + 1, W - 1);
        int iyB = min(iyT + 1, H - 1);
        float* outx = out + (size_t)bb * 2 * HW;
        float* outy = outx + HW;
        float* cp   = cnt_plane + (size_t)bb * HW;
        int o00 = iyT * W + ixL, o01 = iyT * W + ixR;
        int o10 = iyB * W + ixL, o11 = iyB * W + ixR;
        atomicAdd(&cp[o00], rec.y);   atomicAdd(&cp[o01], rec.y);
        atomicAdd(&cp[o10], rec.y);   atomicAdd(&cp[o11], rec.y);
        atomicAdd(&outx[o00], rec.z); atomicAdd(&outx[o01], rec.z);
        atomicAdd(&outx[o10], rec.z); atomicAdd(&outx[o11], rec.z);
        atomicAdd(&outy[o00], rec.w); atomicAdd(&outy[o01], rec.w);
        atomicAdd(&outy[o10], rec.w); atomicAdd(&outy[o11], rec.w);
    }
}

// Kernel 3: normalize (raw sums / count), float4-vectorized
__global__ void dfp_normalize(float* __restrict__ out,
                              const float* __restrict__ count, int B)
{
    constexpr int HW4 = HW / 4;
    const long total4 = (long)B * HW4;
    long i = (long)blockIdx.x * blockDim.x + threadIdx.x;
    if (i >= total4) return;
    int b = (int)(i / HW4);
    int p = (int)(i - (long)b * HW4);

    float4 c = ((const float4*)count)[(size_t)b * HW4 + p];
    float4* ox = (float4*)(out + (size_t)b * 2 * HW) + p;
    float4* oy = (float4*)(out + (size_t)b * 2 * HW + HW) + p;
    float4 x = *ox, y = *oy;
    float d0 = c.x > 0.f ? c.x : 1.f;
    float d1 = c.y > 0.f ? c.y : 1.f;
    float d2 = c.z > 0.f ? c.z : 1.f;
    float d3 = c.w > 0.f ? c.w : 1.f;
    *ox = make_float4(x.x / d0, x.y / d1, x.z / d2, x.w / d3);
    *oy = make_float4(y.x / d0, y.y / d1, y.z / d2, y.w / d3);
}

// ---------------- fallback (round-1) path if ws is too small ----------------

__global__ void dfp_scatter(const float* __restrict__ flow,
                            const float* __restrict__ depth,
                            float* __restrict__ out,
                            float* __restrict__ count, int B)
{
    const long total = (long)B * HW;
    long idx = (long)blockIdx.x * blockDim.x + threadIdx.x;
    if (idx >= total) return;
    int b = (int)(idx / HW);
    int p = (int)(idx - (long)b * HW);
    int y = p / W;
    int x = p - y * W;
    const float* f = flow + (size_t)b * 2 * HW;
    float fx = f[p], fy = f[HW + p], d = depth[idx];
    float x2 = (float)x + fx, y2 = (float)y + fy;
    if (!(x2 >= 0.f && y2 >= 0.f && x2 <= (float)(W - 1) && y2 <= (float)(H - 1)))
        return;
    int ixL = min(max((int)floorf(x2), 0), W - 1);
    int iyT = min(max((int)floorf(y2), 0), H - 1);
    int ixR = min(ixL + 1, W - 1), iyB = min(iyT + 1, H - 1);
    float vx = -fx * d, vy = -fy * d;
    float* cnt_b  = count + (size_t)b * HW;
    float* outx_b = out + (size_t)b * 2 * HW;
    float* outy_b = outx_b + HW;
    int o00 = iyT * W + ixL, o01 = iyT * W + ixR;
    int o10 = iyB * W + ixL, o11 = iyB * W + ixR;
    atomicAdd(&cnt_b[o00], d);   atomicAdd(&cnt_b[o01], d);
    atomicAdd(&cnt_b[o10], d);   atomicAdd(&cnt_b[o11], d);
    atomicAdd(&outx_b[o00], vx); atomicAdd(&outx_b[o01], vx);
    atomicAdd(&outx_b[o10], vx); atomicAdd(&outx_b[o11], vx);
    atomicAdd(&outy_b[o00], vy); atomicAdd(&outy_b[o01], vy);
    atomicAdd(&outy_b[o10], vy); atomicAdd(&outy_b[o11], vy);
}

__global__ void dfp_normalize_scalar(float* __restrict__ out,
                                     const float* __restrict__ count, int B)
{
    const long total = (long)B * HW;
    long idx = (long)blockIdx.x * blockDim.x + threadIdx.x;
    if (idx >= total) return;
    int b = (int)(idx / HW);
    int p = (int)(idx - (long)b * HW);
    float c = count[idx];
    float den = (c > 0.f) ? c : 1.f;
    size_t o = (size_t)b * 2 * HW + p;
    out[o]      = out[o] / den;
    out[o + HW] = out[o + HW] / den;
}

extern "C" void kernel_launch(void* const* d_in, const int* in_sizes, int n_in,
                              void* d_out, int out_size, void* d_ws, size_t ws_size,
                              hipStream_t stream) {
    const float* flow  = (const float*)d_in[0];
    const float* depth = (const float*)d_in[1];
    float* out = (float*)d_out;

    const int B = in_sizes[1] / HW;
    const long total = (long)B * HW;

    const size_t plane_bytes = (size_t)total * sizeof(float);
    const int grid = B * TX * TY;

    if (ws_size >= plane_bytes + (1u << 20)) {
        float*    cnt  = (float*)d_ws;
        unsigned* lcnt = (unsigned*)((char*)d_ws + plane_bytes);
        float4*   list = (float4*)((char*)d_ws + plane_bytes + 16);
        unsigned  cap  = (unsigned)((ws_size - plane_bytes - 16) / sizeof(float4));

        const long total4 = total / 4;
        const int n_threads = 256;
        const int n_blocks  = (int)((total4 + n_threads - 1) / n_threads);

        hipMemsetAsync(lcnt, 0, 16, stream);
        dfp_tile<<<grid, 512, 0, stream>>>(flow, depth, cnt, lcnt, list, cap, out, B);
        dfp_leak_apply<<<256, 256, 0, stream>>>(list, lcnt, out, cnt, cap, B);
        dfp_normalize<<<n_blocks, n_threads, 0, stream>>>(out, cnt, B);
    } else {
        const int threads = 256;
        const int blocks = (int)((total + threads - 1) / threads);
        float* cnt = (float*)d_ws;
        hipMemsetAsync(d_out, 0, (size_t)total * 2 * sizeof(float), stream);
        hipMemsetAsync(d_ws, 0, plane_bytes, stream);
        dfp_scatter<<<blocks, threads, 0, stream>>>(flow, depth, out, cnt, B);
        dfp_normalize_scalar<<<blocks, threads, 0, stream>>>(out, cnt, B);
    }
}

// Round 12
// 215.871 us; speedup vs baseline: 3.4873x; 3.4873x over previous
//
#include <hip/hip_runtime.h>

// DepthFlowProjection (DAIN, fillhole=0) forward — LDS box-splat scatter.
// R12 = R9's proven tile hot path (float4 row loads, stride-4 lanes, 2-deep
// pipeline, branchy corner adds) + per-block leak SEGMENT append.
// R10/R11 lesson: __ballot/__shfl (convergent) + global atomicAdd-with-
// return in the inner loop's rare branch linearize control flow (no
// s_cbranch_execz skip) and stall every iteration on the atomic's vmcnt
// return (~4x collapse, VALU 30%->7.5%). The append must be (a) free of
// convergent ops and (b) return-latency-cheap: LDS counter (ds_add_rtn,
// ~40cy) + plain global store into this block's private segment.

constexpr int W  = 1920, H = 1080;
constexpr int HW = W * H;
constexpr int Sh = 20, Wt = 128, R = 24;
constexpr int TX = W / Wt, TY = H / Sh;     // 15, 54
constexpr int SW = Sh * Wt;                 // 2560 outputs per tile
constexpr int SP = (Sh + 1) * (Wt + 1);     // 2709 S-cells per plane (stride 129)
constexpr int ACCN = (3 * SP + 3) & ~3;     // 8128 floats (32.5 KB)
constexpr float LEAK_THR = (float)(R - 1);  // 23.0f
constexpr int LEAK_K = 512;                 // records per block segment (mean ~20)

__global__ __launch_bounds__(512, 8) void dfp_tile(
    const float* __restrict__ flow, const float* __restrict__ depth,
    float* __restrict__ cnt_out,        // [B*HW] raw tile cnt plane
    unsigned* __restrict__ leak_counts, // [gridDim.x]
    float4* __restrict__ leak_list,     // [gridDim.x * LEAK_K]
    float* __restrict__ out, int B)
{
    __shared__ __align__(16) float acc[ACCN];   // S planes: cnt, sx, sy
    __shared__ unsigned s_lcnt;
    const int tid  = threadIdx.x;
    const int lane = tid & 63;
    const int wid  = tid >> 6;

    // XCD-aware swizzle (grid = 3240, mod 8 == 0 -> simple bijective form)
    int nwg  = gridDim.x;
    int orig = blockIdx.x;
    int blk  = ((nwg & 7) == 0) ? (orig & 7) * (nwg >> 3) + (orig >> 3) : orig;

    int b  = blk / (TX * TY);
    int t  = blk - b * (TX * TY);
    int ty = t / TX;
    int tx = t - ty * TX;
    const int Y0 = ty * Sh, X0 = tx * Wt;

    float4* accv = (float4*)acc;
    for (int i = tid; i < ACCN / 4; i += 512)
        accv[i] = make_float4(0.f, 0.f, 0.f, 0.f);
    if (tid == 0) s_lcnt = 0u;
    __syncthreads();

    const float* fxp = flow + (size_t)b * 2 * HW;
    const float* fyp = fxp + HW;
    const float* dp  = depth + (size_t)b * HW;

    const int r0 = max(Y0 - R, 0), r1 = min(Y0 + Sh + R, H);
    const int c0 = max(X0 - R, 0), c1 = min(X0 + Wt + R, W);
    // c1-c0 is a multiple of 4 (X0 mult of 128, R=24, W=1920)
    const int nlv = (c1 - c0) >> 2;      // # valid lanes (<= 44)
    const int ce  = c0 + (lane << 2);
    const int cl  = min(ce, c1 - 4);

    auto ldrow = [&](int r, float4& f4x, float4& f4y, float4& d4) {
        size_t p = (size_t)r * W + cl;
        f4x = *(const float4*)(fxp + p);
        f4y = *(const float4*)(fyp + p);
        d4  = *(const float4*)(dp  + p);
    };

    auto proc1 = [&](int row, int col, float fx, float fy, float dv) {
        float x2 = (float)col + fx;
        float y2 = (float)row + fy;
        if (!(x2 >= 0.f && y2 >= 0.f && x2 <= (float)(W - 1) && y2 <= (float)(H - 1)))
            return;
        int ixL = (int)floorf(x2);    // valid => in [0, W-1]
        int iyT = (int)floorf(y2);    // valid => in [0, H-1]
        float vx = -fx * dv, vy = -fy * dv;
        bool small = (fabsf(fx) <= LEAK_THR) && (fabsf(fy) <= LEAK_THR);
        bool dup   = (ixL >= W - 1) | (iyT >= H - 1);  // border clamp dup case

        if (small && !dup) {
            // base-corner accumulate into overlapping S-window
            // (boundary rows/cols stored by BOTH adjacent tiles; each copy
            // feeds only that tile's exclusive outputs -> exact)
            int a = iyT - Y0 + 1;
            int c = ixL - X0 + 1;
            if ((unsigned)a < (unsigned)(Sh + 1) && (unsigned)c < (unsigned)(Wt + 1)) {
                int o = a * (Wt + 1) + c;
                atomicAdd(&acc[o],          dv);
                atomicAdd(&acc[o + SP],     vx);
                atomicAdd(&acc[o + 2*SP],   vy);
            }
        } else if ((unsigned)(row - Y0) < (unsigned)Sh &&
                   (unsigned)(col - X0) < (unsigned)Wt) {
            // rare pixel (big flow / border dup): append one record, once,
            // by its source-owning tile, into this block's private segment.
            // LDS counter (fast return, non-convergent) + plain global store
            // -> branch stays execz-skippable.
            unsigned idx = atomicAdd(&s_lcnt, 1u);
            if (idx < (unsigned)LEAK_K)
                leak_list[(size_t)blk * LEAK_K + idx] = make_float4(
                    __int_as_float(b * HW + iyT * W + ixL), dv, vx, vy);
        }
    };

    auto proc4 = [&](int row, const float4& f4x, const float4& f4y, const float4& d4) {
        if (lane >= nlv) return;         // duplicate tail lanes: nothing to do
        proc1(row, cl + 0, f4x.x, f4y.x, d4.x);
        proc1(row, cl + 1, f4x.y, f4y.y, d4.y);
        proc1(row, cl + 2, f4x.z, f4y.z, d4.z);
        proc1(row, cl + 3, f4x.w, f4y.w, d4.w);
    };

    // 2-deep software-pipelined row loop; named slots A/B (static indexing)
    int r = r0 + wid;
    float4 fxA, fyA, dA, fxB, fyB, dB;
    if (r     < r1) ldrow(r,     fxA, fyA, dA);
    if (r + 8 < r1) ldrow(r + 8, fxB, fyB, dB);
    while (r < r1) {
        if (r + 16 < r1) {
            float4 t1, t2, t3;
            ldrow(r + 16, t1, t2, t3);
            proc4(r, fxA, fyA, dA);
            fxA = t1; fyA = t2; dA = t3;
        } else {
            proc4(r, fxA, fyA, dA);
        }
        r += 8;
        if (r >= r1) break;
        if (r + 16 < r1) {
            float4 t1, t2, t3;
            ldrow(r + 16, t1, t2, t3);
            proc4(r, fxB, fyB, dB);
            fxB = t1; fyB = t2; dB = t3;
        } else {
            proc4(r, fxB, fyB, dB);
        }
        r += 8;
    }
    __syncthreads();

    if (tid == 0) leak_counts[blk] = min(s_lcnt, (unsigned)LEAK_K);

    // flush: 2x2 window sum of S -> raw output sums (exclusive ownership)
    float* outx = out + (size_t)b * 2 * HW;
    float* outy = outx + HW;
    for (int i = tid; i < SW; i += 512) {
        int ly = i >> 7;            // Wt = 128
        int lx = i & 127;
        int o  = ly * (Wt + 1) + lx;
        float cnt = acc[o]        + acc[o + 1]
                  + acc[o + Wt+1] + acc[o + Wt+2];
        float sx  = acc[SP + o]        + acc[SP + o + 1]
                  + acc[SP + o + Wt+1] + acc[SP + o + Wt+2];
        float sy  = acc[2*SP + o]        + acc[2*SP + o + 1]
                  + acc[2*SP + o + Wt+1] + acc[2*SP + o + Wt+2];
        int gp = (Y0 + ly) * W + (X0 + lx);
        outx[gp] = sx;
        outy[gp] = sy;
        cnt_out[(size_t)b * HW + gp] = cnt;
    }
}

// Kernel 2: apply leak records (reference-style 4 clamped corners) via
// fire-and-forget global atomics. Stream-ordered after dfp_tile.
__global__ void dfp_leak_apply(const float4* __restrict__ list,
                               const unsigned* __restrict__ counts,
                               float* __restrict__ out,
                               float* __restrict__ cnt_plane, int B)
{
    int blk = blockIdx.x;
    unsigned n = counts[blk];
    if (n > (unsigned)LEAK_K) n = LEAK_K;
    const float4* seg = list + (size_t)blk * LEAK_K;
    for (unsigned i = threadIdx.x; i < n; i += blockDim.x) {
        float4 rec = seg[i];
        int pos = __float_as_int(rec.x);
        int bb  = pos / HW;
        int p   = pos - bb * HW;
        int iyT = p / W;
        int ixL = p - iyT * W;
        int ixR = min(ixL + 1, W - 1);
        int iyB = min(iyT + 1, H - 1);
        float* outx = out + (size_t)bb * 2 * HW;
        float* outy = outx + HW;
        float* cp   = cnt_plane + (size_t)bb * HW;
        int o00 = iyT * W + ixL, o01 = iyT * W + ixR;
        int o10 = iyB * W + ixL, o11 = iyB * W + ixR;
        atomicAdd(&cp[o00], rec.y);   atomicAdd(&cp[o01], rec.y);
        atomicAdd(&cp[o10], rec.y);   atomicAdd(&cp[o11], rec.y);
        atomicAdd(&outx[o00], rec.z); atomicAdd(&outx[o01], rec.z);
        atomicAdd(&outx[o10], rec.z); atomicAdd(&outx[o11], rec.z);
        atomicAdd(&outy[o00], rec.w); atomicAdd(&outy[o01], rec.w);
        atomicAdd(&outy[o10], rec.w); atomicAdd(&outy[o11], rec.w);
    }
}

// Kernel 3: normalize (raw sums / count), float4-vectorized
__global__ void dfp_normalize(float* __restrict__ out,
                              const float* __restrict__ count, int B)
{
    constexpr int HW4 = HW / 4;
    const long total4 = (long)B * HW4;
    long i = (long)blockIdx.x * blockDim.x + threadIdx.x;
    if (i >= total4) return;
    int b = (int)(i / HW4);
    int p = (int)(i - (long)b * HW4);

    float4 c = ((const float4*)count)[(size_t)b * HW4 + p];
    float4* ox = (float4*)(out + (size_t)b * 2 * HW) + p;
    float4* oy = (float4*)(out + (size_t)b * 2 * HW + HW) + p;
    float4 x = *ox, y = *oy;
    float d0 = c.x > 0.f ? c.x : 1.f;
    float d1 = c.y > 0.f ? c.y : 1.f;
    float d2 = c.z > 0.f ? c.z : 1.f;
    float d3 = c.w > 0.f ? c.w : 1.f;
    *ox = make_float4(x.x / d0, x.y / d1, x.z / d2, x.w / d3);
    *oy = make_float4(y.x / d0, y.y / d1, y.z / d2, y.w / d3);
}

// ---------------- fallback (round-1) path if ws is too small ----------------

__global__ void dfp_scatter(const float* __restrict__ flow,
                            const float* __restrict__ depth,
                            float* __restrict__ out,
                            float* __restrict__ count, int B)
{
    const long total = (long)B * HW;
    long idx = (long)blockIdx.x * blockDim.x + threadIdx.x;
    if (idx >= total) return;
    int b = (int)(idx / HW);
    int p = (int)(idx - (long)b * HW);
    int y = p / W;
    int x = p - y * W;
    const float* f = flow + (size_t)b * 2 * HW;
    float fx = f[p], fy = f[HW + p], d = depth[idx];
    float x2 = (float)x + fx, y2 = (float)y + fy;
    if (!(x2 >= 0.f && y2 >= 0.f && x2 <= (float)(W - 1) && y2 <= (float)(H - 1)))
        return;
    int ixL = min(max((int)floorf(x2), 0), W - 1);
    int iyT = min(max((int)floorf(y2), 0), H - 1);
    int ixR = min(ixL + 1, W - 1), iyB = min(iyT + 1, H - 1);
    float vx = -fx * d, vy = -fy * d;
    float* cnt_b  = count + (size_t)b * HW;
    float* outx_b = out + (size_t)b * 2 * HW;
    float* outy_b = outx_b + HW;
    int o00 = iyT * W + ixL, o01 = iyT * W + ixR;
    int o10 = iyB * W + ixL, o11 = iyB * W + ixR;
    atomicAdd(&cnt_b[o00], d);   atomicAdd(&cnt_b[o01], d);
    atomicAdd(&cnt_b[o10], d);   atomicAdd(&cnt_b[o11], d);
    atomicAdd(&outx_b[o00], vx); atomicAdd(&outx_b[o01], vx);
    atomicAdd(&outx_b[o10], vx); atomicAdd(&outx_b[o11], vx);
    atomicAdd(&outy_b[o00], vy); atomicAdd(&outy_b[o01], vy);
    atomicAdd(&outy_b[o10], vy); atomicAdd(&outy_b[o11], vy);
}

__global__ void dfp_normalize_scalar(float* __restrict__ out,
                                     const float* __restrict__ count, int B)
{
    const long total = (long)B * HW;
    long idx = (long)blockIdx.x * blockDim.x + threadIdx.x;
    if (idx >= total) return;
    int b = (int)(idx / HW);
    int p = (int)(idx - (long)b * HW);
    float c = count[idx];
    float den = (c > 0.f) ? c : 1.f;
    size_t o = (size_t)b * 2 * HW + p;
    out[o]      = out[o] / den;
    out[o + HW] = out[o + HW] / den;
}

extern "C" void kernel_launch(void* const* d_in, const int* in_sizes, int n_in,
                              void* d_out, int out_size, void* d_ws, size_t ws_size,
                              hipStream_t stream) {
    const float* flow  = (const float*)d_in[0];
    const float* depth = (const float*)d_in[1];
    float* out = (float*)d_out;

    const int B = in_sizes[1] / HW;
    const long total = (long)B * HW;
    const int grid = B * TX * TY;

    const size_t plane_bytes  = (size_t)total * sizeof(float);
    const size_t counts_bytes = ((size_t)grid * sizeof(unsigned) + 255) & ~(size_t)255;
    const size_t list_bytes   = (size_t)grid * LEAK_K * sizeof(float4);

    if (ws_size >= plane_bytes + counts_bytes + list_bytes) {
        float*    cnt    = (float*)d_ws;
        unsigned* counts = (unsigned*)((char*)d_ws + plane_bytes);
        float4*   list   = (float4*)((char*)d_ws + plane_bytes + counts_bytes);

        const long total4 = total / 4;
        const int n_threads = 256;
        const int n_blocks  = (int)((total4 + n_threads - 1) / n_threads);

        dfp_tile<<<grid, 512, 0, stream>>>(flow, depth, cnt, counts, list, out, B);
        dfp_leak_apply<<<grid, 64, 0, stream>>>(list, counts, out, cnt, B);
        dfp_normalize<<<n_blocks, n_threads, 0, stream>>>(out, cnt, B);
    } else {
        const int threads = 256;
        const int blocks = (int)((total + threads - 1) / threads);
        float* cnt = (float*)d_ws;
        hipMemsetAsync(d_out, 0, (size_t)total * 2 * sizeof(float), stream);
        hipMemsetAsync(d_ws, 0, plane_bytes, stream);
        dfp_scatter<<<blocks, threads, 0, stream>>>(flow, depth, out, cnt, B);
        dfp_normalize_scalar<<<blocks, threads, 0, stream>>>(out, cnt, B);
    }
}